// Round 6
// baseline (576.162 us; speedup 1.0000x reference)
//
#include <hip/hip_runtime.h>

#define H512 512

typedef short bf16x8 __attribute__((ext_vector_type(8)));
typedef float f32x4  __attribute__((ext_vector_type(4)));

__device__ __forceinline__ float silu_f(float v) { return v / (1.0f + __expf(-v)); }

__device__ __forceinline__ short f2bf(float f) {   // RNE float -> bf16 bits
    unsigned u = __float_as_uint(f);
    u = (u + 0x7FFFu + ((u >> 16) & 1u)) >> 16;
    return (short)u;
}
__device__ __forceinline__ float bf2f(short s) {
    return __uint_as_float(((unsigned)(unsigned short)s) << 16);
}

// bijective XCD-chunked swizzle (m204): physical block id -> logical wg id
__device__ __forceinline__ int xcd_swz(int b, int nwg) {
    const int NX = 8;
    int q = nwg / NX, rr = nwg % NX;
    int xcd = b % NX, idx = b / NX;
    int base = (xcd < rr) ? xcd * (q + 1) : rr * (q + 1) + (xcd - rr) * q;
    return base + idx;
}

// ---------------- CSR build ----------------

__global__ void hist_kernel(const int* __restrict__ row, const int* __restrict__ col,
                            float* __restrict__ deg, int* __restrict__ cnt, int E) {
    int e = blockIdx.x * blockDim.x + threadIdx.x;
    if (e < E) {
        atomicAdd(&deg[row[e]], 1.0f);
        atomicAdd(&cnt[col[e]], 1);
    }
}

__global__ void dinv_kernel(const float* __restrict__ deg, float* __restrict__ dinv, int n) {
    int i = blockIdx.x * blockDim.x + threadIdx.x;
    if (i < n) {
        float d = deg[i];
        dinv[i] = d > 0.0f ? rsqrtf(fmaxf(d, 1e-12f)) : 0.0f;
    }
}

// ---- 3-phase multi-block exclusive scan of cnt[n] -> ptr[n+1], ptr2[n] ----

__global__ __launch_bounds__(256) void bsum_kernel(const int* __restrict__ cnt,
                                                   int* __restrict__ bsum, int n) {
    __shared__ int s[4];
    int i = blockIdx.x * 256 + threadIdx.x;
    int v = (i < n) ? cnt[i] : 0;
    #pragma unroll
    for (int off = 32; off; off >>= 1) v += __shfl_down(v, off, 64);
    if ((threadIdx.x & 63) == 0) s[threadIdx.x >> 6] = v;
    __syncthreads();
    if (threadIdx.x == 0) bsum[blockIdx.x] = s[0] + s[1] + s[2] + s[3];
}

__global__ __launch_bounds__(256) void bscan_kernel(const int* __restrict__ bsum,
                                                    int* __restrict__ boff, int B) {
    __shared__ int s[256];
    int tid = threadIdx.x;
    int v = (tid < B) ? bsum[tid] : 0;
    s[tid] = v;
    __syncthreads();
    #pragma unroll
    for (int off = 1; off < 256; off <<= 1) {
        int t = (tid >= off) ? s[tid - off] : 0;
        __syncthreads();
        s[tid] += t;
        __syncthreads();
    }
    if (tid < B) boff[tid] = s[tid] - v;   // exclusive
}

__global__ __launch_bounds__(256) void cscan_kernel(const int* __restrict__ cnt,
                                                    const int* __restrict__ boff,
                                                    int* __restrict__ ptr,
                                                    int* __restrict__ ptr2, int n, int B) {
    __shared__ int s[256];
    int b = blockIdx.x, tid = threadIdx.x;
    int i = b * 256 + tid;
    int v = (i < n) ? cnt[i] : 0;
    s[tid] = v;
    __syncthreads();
    #pragma unroll
    for (int off = 1; off < 256; off <<= 1) {
        int t = (tid >= off) ? s[tid - off] : 0;
        __syncthreads();
        s[tid] += t;
        __syncthreads();
    }
    int exc = boff[b] + s[tid] - v;
    if (i < n) { ptr[i] = exc; ptr2[i] = exc; }
    if (b == B - 1 && tid == 255) ptr[n] = exc + v;  // grand total
}

__global__ void scatter_kernel(const int* __restrict__ row, const int* __restrict__ col,
                               const float* __restrict__ dinv, int* __restrict__ ptr2,
                               int* __restrict__ esrc, float* __restrict__ ew, int E) {
    int e = blockIdx.x * blockDim.x + threadIdx.x;
    if (e >= E) return;
    int r = row[e], c = col[e];
    int pos = atomicAdd(&ptr2[c], 1);
    esrc[pos] = r;
    ew[pos]   = -dinv[r] * dinv[c];
}

// ---------------- converts ----------------

// Wt[n][k] = bf16(W[k][n]) via 32x32 LDS tile (coalesced read AND write)
__global__ __launch_bounds__(256) void wt_kernel(const float* __restrict__ W,
                                                 short* __restrict__ Wt, int K, int Nw) {
    __shared__ float tile[32][33];
    const int tx = threadIdx.x & 31;
    const int ty = threadIdx.x >> 5;       // 0..7
    const int nt = Nw / 32;
    const int k0 = (blockIdx.x / nt) * 32;
    const int n0 = (blockIdx.x % nt) * 32;
    #pragma unroll
    for (int i = 0; i < 4; ++i) {
        const int k = ty + i * 8;
        tile[k][tx] = W[(size_t)(k0 + k) * Nw + n0 + tx];
    }
    __syncthreads();
    #pragma unroll
    for (int i = 0; i < 4; ++i) {
        const int a = ty + i * 8;          // n-local
        Wt[(size_t)(n0 + a) * K + k0 + tx] = f2bf(tile[tx][a]);
    }
}

// xb[MPAD][256] = bf16(x), zero-padded rows
__global__ void xconv_kernel(const float* __restrict__ x, short* __restrict__ xb,
                             int Nreal, int Mpad) {
    int tid = blockIdx.x * blockDim.x + threadIdx.x;
    if (tid >= Mpad * 32) return;
    int r = tid >> 5, c8 = (tid & 31) * 8;
    bf16x8 o = {0, 0, 0, 0, 0, 0, 0, 0};
    if (r < Nreal) {
        const float4 f0 = *(const float4*)(x + (size_t)r * 256 + c8);
        const float4 f1 = *(const float4*)(x + (size_t)r * 256 + c8 + 4);
        o[0] = f2bf(f0.x); o[1] = f2bf(f0.y); o[2] = f2bf(f0.z); o[3] = f2bf(f0.w);
        o[4] = f2bf(f1.x); o[5] = f2bf(f1.y); o[6] = f2bf(f1.z); o[7] = f2bf(f1.w);
    }
    *(bf16x8*)(xb + (size_t)r * 256 + c8) = o;
}

// ---------------- gather prop: U[node,:] = sum_in w * T[src,:]  (bf16 in/out) ----------------

__global__ __launch_bounds__(256) void gather_kernel(
    const int* __restrict__ ptr, const int* __restrict__ esrc,
    const float* __restrict__ ew, const short* __restrict__ T,
    short* __restrict__ U, int N_)
{
    int t = threadIdx.x;
    int node = blockIdx.x * 4 + (t >> 6);
    if (node >= N_) return;
    int q = (t & 63) * 8;
    float acc[8] = {0.f, 0.f, 0.f, 0.f, 0.f, 0.f, 0.f, 0.f};
    const int i1 = ptr[node + 1];
    for (int i = ptr[node]; i < i1; ++i) {
        int s   = esrc[i];
        float w = ew[i];
        bf16x8 tv = *(const bf16x8*)(T + (size_t)s * H512 + q);
        #pragma unroll
        for (int j = 0; j < 8; ++j) acc[j] += w * bf2f(tv[j]);
    }
    bf16x8 o;
    #pragma unroll
    for (int j = 0; j < 8; ++j) o[j] = f2bf(acc[j]);
    *(bf16x8*)(U + (size_t)node * H512 + q) = o;
}

// ---------------- bf16 MFMA GEMM ----------------
// Cout[M,Nw] = op( (ACCUM? bf2f(Cin) : 0) + A @ Bt^T + (BIAS? bias : 0) ), op=SiLU opt.
// A: bf16 [MPAD][lda], Bt: bf16 [Nw][ldb], tile 128x128, BK=64, 4 waves (2x2).
// Staging: global_load_lds(16B), XOR-swizzled SOURCE (linear LDS dest), reads
// swizzled byte ^= ((row&7)<<4).  Epilogue: f32 re-staged through LDS in two
// 64-col passes (+4*(row&15) col rotation) -> coalesced bf16x8/f32x4 I/O.
// Grid is 1-D (gx*gy) with bijective XCD-chunked swizzle.

template<int ACCUM, int BIAS, int SILU, int F32OUT>
__global__ __launch_bounds__(256) void mfma_gemm(
    const short* __restrict__ A, int lda,
    const short* __restrict__ Bt, int ldb,
    const short* __restrict__ Cin, void* __restrict__ Cout, int ldc,
    const float* __restrict__ bias, int Mreal, int K, int gx)
{
    __shared__ alignas(16) short lds[2 * 128 * 64];
    short* As = lds;
    short* Bs = lds + 128 * 64;

    const int t    = threadIdx.x;
    const int lane = t & 63;
    const int wid  = t >> 6;

    const int wg = xcd_swz(blockIdx.x, gridDim.x);
    const int m0 = (wg / gx) * 128;
    const int n0 = (wg % gx) * 128;

    const int wm   = wid >> 1;
    const int wn   = wid & 1;

    const int srow  = lane >> 3;            // 0..7
    const int scol  = (lane & 7) * 16;      // byte col, 0..112
    const int corig = scol ^ (srow << 4);   // inverse-swizzled source byte col
    const int cel   = corig >> 1;           // source element offset

    f32x4 acc[4][4];
    #pragma unroll
    for (int m = 0; m < 4; ++m)
        #pragma unroll
        for (int n = 0; n < 4; ++n)
            acc[m][n] = (f32x4){0.f, 0.f, 0.f, 0.f};

    const int r = lane & 15;
    const int g = lane >> 4;

    for (int k0 = 0; k0 < K; k0 += 64) {
        #pragma unroll
        for (int i = 0; i < 4; ++i) {
            const int r0 = (wid * 4 + i) * 8;
            const short* ga = A  + (size_t)(m0 + r0 + srow) * lda + (k0 + cel);
            __builtin_amdgcn_global_load_lds(
                (const __attribute__((address_space(1))) void*)ga,
                (__attribute__((address_space(3))) void*)(As + r0 * 64), 16, 0, 0);
            const short* gb = Bt + (size_t)(n0 + r0 + srow) * ldb + (k0 + cel);
            __builtin_amdgcn_global_load_lds(
                (const __attribute__((address_space(1))) void*)gb,
                (__attribute__((address_space(3))) void*)(Bs + r0 * 64), 16, 0, 0);
        }
        asm volatile("s_waitcnt vmcnt(0)" ::: "memory");
        __syncthreads();

        #pragma unroll
        for (int ks = 0; ks < 2; ++ks) {
            bf16x8 af[4], bfr[4];
            #pragma unroll
            for (int m = 0; m < 4; ++m) {
                const int rowA = wm * 64 + m * 16 + r;
                const int cb   = (ks * 64 + g * 16) ^ ((rowA & 7) << 4);
                af[m] = *(const bf16x8*)((const char*)As + rowA * 128 + cb);
            }
            #pragma unroll
            for (int n = 0; n < 4; ++n) {
                const int rowB = wn * 64 + n * 16 + r;
                const int cb   = (ks * 64 + g * 16) ^ ((rowB & 7) << 4);
                bfr[n] = *(const bf16x8*)((const char*)Bs + rowB * 128 + cb);
            }
            #pragma unroll
            for (int m = 0; m < 4; ++m)
                #pragma unroll
                for (int n = 0; n < 4; ++n)
                    acc[m][n] = __builtin_amdgcn_mfma_f32_16x16x32_bf16(
                        af[m], bfr[n], acc[m][n], 0, 0, 0);
        }
        __syncthreads();
    }

    // ---- epilogue: stage f32 through LDS (two 64-col passes), coalesced I/O ----
    float* fs = (float*)lds;               // [128][64] f32 = 32 KB
    const int rrow = t >> 1;               // read-back row 0..127
    const int hh   = (t & 1) * 32;         // col half within pass
    const int gr   = m0 + rrow;
    const int rsft = (rrow & 15) << 2;

    #pragma unroll
    for (int p = 0; p < 2; ++p) {
        if (wn == p) {                     // this wave-group owns cols p*64..p*64+63
            #pragma unroll
            for (int m = 0; m < 4; ++m) {
                #pragma unroll
                for (int j = 0; j < 4; ++j) {
                    const int row = wm * 64 + m * 16 + g * 4 + j;
                    const int sft = (row & 15) << 2;
                    #pragma unroll
                    for (int n = 0; n < 4; ++n) {
                        const int cl = (n * 16 + r + sft) & 63;
                        fs[row * 64 + cl] = acc[m][n][j];
                    }
                }
            }
        }
        __syncthreads();

        {
            const int gcb = n0 + p * 64 + hh;
            float vv[32];
            #pragma unroll
            for (int c4 = 0; c4 < 8; ++c4) {
                const int cl = (hh + c4 * 4 + rsft) & 63;
                *(f32x4*)&vv[c4 * 4] = *(const f32x4*)&fs[rrow * 64 + cl];
            }
            if (ACCUM) {
                #pragma unroll
                for (int c8 = 0; c8 < 4; ++c8) {
                    bf16x8 ci = *(const bf16x8*)(Cin + (size_t)gr * ldc + gcb + c8 * 8);
                    #pragma unroll
                    for (int j = 0; j < 8; ++j) vv[c8 * 8 + j] += bf2f(ci[j]);
                }
            }
            if (BIAS) {
                #pragma unroll
                for (int c4 = 0; c4 < 8; ++c4) {
                    const float4 bv = *(const float4*)(bias + gcb + c4 * 4);
                    vv[c4 * 4 + 0] += bv.x; vv[c4 * 4 + 1] += bv.y;
                    vv[c4 * 4 + 2] += bv.z; vv[c4 * 4 + 3] += bv.w;
                }
            }
            if (SILU) {
                #pragma unroll
                for (int j = 0; j < 32; ++j) vv[j] = silu_f(vv[j]);
            }
            if (F32OUT) {
                if (gr < Mreal) {
                    #pragma unroll
                    for (int c4 = 0; c4 < 8; ++c4)
                        *(float4*)((float*)Cout + (size_t)gr * ldc + gcb + c4 * 4) =
                            make_float4(vv[c4*4+0], vv[c4*4+1], vv[c4*4+2], vv[c4*4+3]);
                }
            } else {
                #pragma unroll
                for (int c8 = 0; c8 < 4; ++c8) {
                    bf16x8 o;
                    #pragma unroll
                    for (int j = 0; j < 8; ++j) o[j] = f2bf(vv[c8 * 8 + j]);
                    *(bf16x8*)((short*)Cout + (size_t)gr * ldc + gcb + c8 * 8) = o;
                }
            }
        }
        __syncthreads();
    }
}

// ---------------- launcher ----------------
// Workspace (MPAD=50048): h0,h1,T,U bf16 51.25 MB each = 205.0 MB
//   + weights bf16 2.62 MB + CSR/misc ~4.5 MB  ~= 212 MB.  xb aliases T.

extern "C" void kernel_launch(void* const* d_in, const int* in_sizes, int n_in,
                              void* d_out, int out_size, void* d_ws, size_t ws_size,
                              hipStream_t stream)
{
    const float* x      = (const float*)d_in[0];
    const int*   ei     = (const int*)  d_in[1];
    const float* in_w   = (const float*)d_in[2];
    const float* in_b   = (const float*)d_in[3];
    const float* conv_w = (const float*)d_in[4];
    const float* conv_b = (const float*)d_in[5];
    const float* out_w  = (const float*)d_in[6];
    const float* out_b  = (const float*)d_in[7];

    const int N = in_sizes[0] / 256;           // 50000
    const int E = in_sizes[1] / 2;             // 400000
    const int MPAD = ((N + 127) / 128) * 128;  // 50048
    const int* row = ei;
    const int* col = ei + E;

    char* p = (char*)d_ws;
    short* h0 = (short*)p; p += (size_t)MPAD * H512 * 2;
    short* h1 = (short*)p; p += (size_t)MPAD * H512 * 2;
    short* T  = (short*)p; p += (size_t)MPAD * H512 * 2;
    short* U  = (short*)p; p += (size_t)MPAD * H512 * 2;
    short* xb = T;  // alias: xb dead before T is first written
    short* wti = (short*)p; p += (size_t)512 * 256 * 2;      // in_w^T  [512][256]
    short* wtc = (short*)p; p += (size_t)4 * 512 * 512 * 2;  // conv_w^T [4][512][512]
    short* wto = (short*)p; p += (size_t)256 * 512 * 2;      // out_w^T [256][512]
    float* deg  = (float*)p; p += (size_t)N * 4;
    float* dinv = (float*)p; p += (size_t)N * 4;
    float* ew   = (float*)p; p += (size_t)E * 4;
    int*   cnt  = (int*)p;   p += (size_t)N * 4;
    int*   ptr  = (int*)p;   p += (size_t)(N + 4) * 4;
    int*   ptr2 = (int*)p;   p += (size_t)N * 4;
    int*   esrc = (int*)p;   p += (size_t)E * 4;
    int*   bsum = (int*)p;   p += (size_t)256 * 4;
    int*   boff = (int*)p;   p += (size_t)256 * 4;

    const int NB = (N + 255) / 256;            // 196 scan blocks

    // CSR build
    hipMemsetAsync(deg, 0, (size_t)N * sizeof(float), stream);
    hipMemsetAsync(cnt, 0, (size_t)N * sizeof(int), stream);
    hist_kernel<<<(E + 255) / 256, 256, 0, stream>>>(row, col, deg, cnt, E);
    dinv_kernel<<<(N + 255) / 256, 256, 0, stream>>>(deg, dinv, N);
    bsum_kernel <<<NB, 256, 0, stream>>>(cnt, bsum, N);
    bscan_kernel<<<1, 256, 0, stream>>>(bsum, boff, NB);
    cscan_kernel<<<NB, 256, 0, stream>>>(cnt, boff, ptr, ptr2, N, NB);
    scatter_kernel<<<(E + 255) / 256, 256, 0, stream>>>(row, col, dinv, ptr2, esrc, ew, E);

    // weight/x converts (wt_kernel: grid = (K/32)*(Nw/32) 32x32 tiles)
    wt_kernel<<<(256 / 32) * (512 / 32), 256, 0, stream>>>(in_w, wti, 256, 512);
    for (int i = 0; i < 4; ++i)
        wt_kernel<<<(512 / 32) * (512 / 32), 256, 0, stream>>>(
            conv_w + (size_t)i * 512 * 512, wtc + (size_t)i * 512 * 512, 512, 512);
    wt_kernel<<<(512 / 32) * (256 / 32), 256, 0, stream>>>(out_w, wto, 512, 256);
    xconv_kernel<<<(MPAD * 32 + 255) / 256, 256, 0, stream>>>(x, xb, N, MPAD);

    const int mt = MPAD / 128;

    // h0 = silu(x @ in_w + in_b)
    mfma_gemm<0, 1, 1, 0><<<dim3(4 * mt), 256, 0, stream>>>(
        xb, 256, wti, 256, nullptr, h0, H512, in_b, N, 256, 4);

    short* hc = h0;
    short* hn = h1;
    for (int l = 0; l < 2; ++l) {
        // T = hc @ W1
        mfma_gemm<0, 0, 0, 0><<<dim3(4 * mt), 256, 0, stream>>>(
            hc, H512, wtc + (size_t)(l * 2 + 1) * 512 * 512, 512,
            nullptr, T, H512, nullptr, N, 512, 4);
        // U = Lhat @ T   (gather, no atomics)
        gather_kernel<<<(N + 3) / 4, 256, 0, stream>>>(ptr, esrc, ew, T, U, N);
        // hn = silu(hc @ W0 + U + b)
        mfma_gemm<1, 1, 1, 0><<<dim3(4 * mt), 256, 0, stream>>>(
            hc, H512, wtc + (size_t)(l * 2 + 0) * 512 * 512, 512,
            U, hn, H512, conv_b + (size_t)l * H512, N, 512, 4);
        short* tmp = hc; hc = hn; hn = tmp;
    }

    // out = hc @ out_w + out_b   (fp32, guarded)
    mfma_gemm<0, 1, 0, 1><<<dim3(2 * mt), 256, 0, stream>>>(
        hc, H512, wto, 512, nullptr, d_out, 256, out_b, N, 512, 2);
}

// Round 7
// 534.473 us; speedup vs baseline: 1.0780x; 1.0780x over previous
//
#include <hip/hip_runtime.h>

#define H512 512

typedef short bf16x8 __attribute__((ext_vector_type(8)));
typedef float f32x4  __attribute__((ext_vector_type(4)));

__device__ __forceinline__ float silu_f(float v) { return v / (1.0f + __expf(-v)); }

__device__ __forceinline__ short f2bf(float f) {   // RNE float -> bf16 bits
    unsigned u = __float_as_uint(f);
    u = (u + 0x7FFFu + ((u >> 16) & 1u)) >> 16;
    return (short)u;
}
__device__ __forceinline__ float bf2f(short s) {
    return __uint_as_float(((unsigned)(unsigned short)s) << 16);
}

// bijective XCD-chunked swizzle (m204): physical block id -> logical wg id
__device__ __forceinline__ int xcd_swz(int b, int nwg) {
    const int NX = 8;
    int q = nwg / NX, rr = nwg % NX;
    int xcd = b % NX, idx = b / NX;
    int base = (xcd < rr) ? xcd * (q + 1) : rr * (q + 1) + (xcd - rr) * q;
    return base + idx;
}

// ---------------- CSR build ----------------

__global__ void hist_kernel(const int* __restrict__ row, const int* __restrict__ col,
                            float* __restrict__ deg, int* __restrict__ cnt, int E) {
    int e = blockIdx.x * blockDim.x + threadIdx.x;
    if (e < E) {
        atomicAdd(&deg[row[e]], 1.0f);
        atomicAdd(&cnt[col[e]], 1);
    }
}

__global__ void dinv_kernel(const float* __restrict__ deg, float* __restrict__ dinv, int n) {
    int i = blockIdx.x * blockDim.x + threadIdx.x;
    if (i < n) {
        float d = deg[i];
        dinv[i] = d > 0.0f ? rsqrtf(fmaxf(d, 1e-12f)) : 0.0f;
    }
}

// ---- 3-phase multi-block exclusive scan of cnt[n] -> ptr[n+1], ptr2[n] ----

__global__ __launch_bounds__(256) void bsum_kernel(const int* __restrict__ cnt,
                                                   int* __restrict__ bsum, int n) {
    __shared__ int s[4];
    int i = blockIdx.x * 256 + threadIdx.x;
    int v = (i < n) ? cnt[i] : 0;
    #pragma unroll
    for (int off = 32; off; off >>= 1) v += __shfl_down(v, off, 64);
    if ((threadIdx.x & 63) == 0) s[threadIdx.x >> 6] = v;
    __syncthreads();
    if (threadIdx.x == 0) bsum[blockIdx.x] = s[0] + s[1] + s[2] + s[3];
}

__global__ __launch_bounds__(256) void bscan_kernel(const int* __restrict__ bsum,
                                                    int* __restrict__ boff, int B) {
    __shared__ int s[256];
    int tid = threadIdx.x;
    int v = (tid < B) ? bsum[tid] : 0;
    s[tid] = v;
    __syncthreads();
    #pragma unroll
    for (int off = 1; off < 256; off <<= 1) {
        int t = (tid >= off) ? s[tid - off] : 0;
        __syncthreads();
        s[tid] += t;
        __syncthreads();
    }
    if (tid < B) boff[tid] = s[tid] - v;   // exclusive
}

__global__ __launch_bounds__(256) void cscan_kernel(const int* __restrict__ cnt,
                                                    const int* __restrict__ boff,
                                                    int* __restrict__ ptr,
                                                    int* __restrict__ ptr2, int n, int B) {
    __shared__ int s[256];
    int b = blockIdx.x, tid = threadIdx.x;
    int i = b * 256 + tid;
    int v = (i < n) ? cnt[i] : 0;
    s[tid] = v;
    __syncthreads();
    #pragma unroll
    for (int off = 1; off < 256; off <<= 1) {
        int t = (tid >= off) ? s[tid - off] : 0;
        __syncthreads();
        s[tid] += t;
        __syncthreads();
    }
    int exc = boff[b] + s[tid] - v;
    if (i < n) { ptr[i] = exc; ptr2[i] = exc; }
    if (b == B - 1 && tid == 255) ptr[n] = exc + v;  // grand total
}

__global__ void scatter_kernel(const int* __restrict__ row, const int* __restrict__ col,
                               const float* __restrict__ dinv, int* __restrict__ ptr2,
                               int* __restrict__ esrc, float* __restrict__ ew, int E) {
    int e = blockIdx.x * blockDim.x + threadIdx.x;
    if (e >= E) return;
    int r = row[e], c = col[e];
    int pos = atomicAdd(&ptr2[c], 1);
    esrc[pos] = r;
    ew[pos]   = -dinv[r] * dinv[c];
}

// ---------------- converts ----------------

// Wt[n][k] = bf16(W[k][n]) via 32x32 LDS tile (coalesced read AND write)
__global__ __launch_bounds__(256) void wt_kernel(const float* __restrict__ W,
                                                 short* __restrict__ Wt, int K, int Nw) {
    __shared__ float tile[32][33];
    const int tx = threadIdx.x & 31;
    const int ty = threadIdx.x >> 5;       // 0..7
    const int nt = Nw / 32;
    const int k0 = (blockIdx.x / nt) * 32;
    const int n0 = (blockIdx.x % nt) * 32;
    #pragma unroll
    for (int i = 0; i < 4; ++i) {
        const int k = ty + i * 8;
        tile[k][tx] = W[(size_t)(k0 + k) * Nw + n0 + tx];
    }
    __syncthreads();
    #pragma unroll
    for (int i = 0; i < 4; ++i) {
        const int a = ty + i * 8;          // n-local
        Wt[(size_t)(n0 + a) * K + k0 + tx] = f2bf(tile[tx][a]);
    }
}

// xb[MPAD][256] = bf16(x), zero-padded rows
__global__ void xconv_kernel(const float* __restrict__ x, short* __restrict__ xb,
                             int Nreal, int Mpad) {
    int tid = blockIdx.x * blockDim.x + threadIdx.x;
    if (tid >= Mpad * 32) return;
    int r = tid >> 5, c8 = (tid & 31) * 8;
    bf16x8 o = {0, 0, 0, 0, 0, 0, 0, 0};
    if (r < Nreal) {
        const float4 f0 = *(const float4*)(x + (size_t)r * 256 + c8);
        const float4 f1 = *(const float4*)(x + (size_t)r * 256 + c8 + 4);
        o[0] = f2bf(f0.x); o[1] = f2bf(f0.y); o[2] = f2bf(f0.z); o[3] = f2bf(f0.w);
        o[4] = f2bf(f1.x); o[5] = f2bf(f1.y); o[6] = f2bf(f1.z); o[7] = f2bf(f1.w);
    }
    *(bf16x8*)(xb + (size_t)r * 256 + c8) = o;
}

// ---------------- gather prop: U[node,:] = sum_in w * T[src,:]  (bf16 in/out) ----------------

__global__ __launch_bounds__(256) void gather_kernel(
    const int* __restrict__ ptr, const int* __restrict__ esrc,
    const float* __restrict__ ew, const short* __restrict__ T,
    short* __restrict__ U, int N_)
{
    int t = threadIdx.x;
    int node = blockIdx.x * 4 + (t >> 6);
    if (node >= N_) return;
    int q = (t & 63) * 8;
    float acc[8] = {0.f, 0.f, 0.f, 0.f, 0.f, 0.f, 0.f, 0.f};
    const int i1 = ptr[node + 1];
    for (int i = ptr[node]; i < i1; ++i) {
        int s   = esrc[i];
        float w = ew[i];
        bf16x8 tv = *(const bf16x8*)(T + (size_t)s * H512 + q);
        #pragma unroll
        for (int j = 0; j < 8; ++j) acc[j] += w * bf2f(tv[j]);
    }
    bf16x8 o;
    #pragma unroll
    for (int j = 0; j < 8; ++j) o[j] = f2bf(acc[j]);
    *(bf16x8*)(U + (size_t)node * H512 + q) = o;
}

// ---------------- bf16 MFMA GEMM ----------------
// Cout[M,Nw] = op( (ACCUM? bf2f(Cin) : 0) + A @ Bt^T + (BIAS? bias : 0) ), op=SiLU opt.
// Tile 128x128, BK=64, 4 waves (2x2). DOUBLE-BUFFERED LDS (2x32KB) with
// counted vmcnt(8) + raw s_barrier: next K-tile's 8 global_load_lds stay in
// flight under the current tile's MFMA (T3/T4-lite; __syncthreads would force
// a vmcnt(0) drain).  Staging src XOR-pre-swizzled, reads byte^=((row&7)<<4).
// Epilogue: single-pass full-tile 128x128 f32 LDS re-stage (64 KB) with
// +4*(row&15) column rotation -> coalesced bf16x8/f32x4 global I/O.
// 1-D grid with bijective XCD-chunked swizzle.

template<int ACCUM, int BIAS, int SILU, int F32OUT>
__global__ __launch_bounds__(256) void mfma_gemm(
    const short* __restrict__ A, int lda,
    const short* __restrict__ Bt, int ldb,
    const short* __restrict__ Cin, void* __restrict__ Cout, int ldc,
    const float* __restrict__ bias, int Mreal, int K, int gx)
{
    __shared__ alignas(16) short lds[4 * 128 * 64];   // 64 KB: 2 x (As+Bs)

    const int t    = threadIdx.x;
    const int lane = t & 63;
    const int wid  = t >> 6;

    const int wg = xcd_swz(blockIdx.x, gridDim.x);
    const int m0 = (wg / gx) * 128;
    const int n0 = (wg % gx) * 128;

    const int wm = wid >> 1;
    const int wn = wid & 1;

    const int srow  = lane >> 3;            // 0..7
    const int scol  = (lane & 7) * 16;      // byte col, 0..112
    const int corig = scol ^ (srow << 4);   // inverse-swizzled source byte col
    const int cel   = corig >> 1;           // source element offset

    f32x4 acc[4][4];
    #pragma unroll
    for (int m = 0; m < 4; ++m)
        #pragma unroll
        for (int n = 0; n < 4; ++n)
            acc[m][n] = (f32x4){0.f, 0.f, 0.f, 0.f};

    const int r = lane & 15;
    const int g = lane >> 4;

    // stage K-tile k0 into buffer buf (8 vmem insts per wave)
    auto stage = [&](int buf, int k0) {
        short* Ad = lds + buf * 16384;
        short* Bd = Ad + 8192;
        #pragma unroll
        for (int i = 0; i < 4; ++i) {
            const int r0 = (wid * 4 + i) * 8;
            const short* ga = A + (size_t)(m0 + r0 + srow) * lda + (k0 + cel);
            __builtin_amdgcn_global_load_lds(
                (const __attribute__((address_space(1))) void*)ga,
                (__attribute__((address_space(3))) void*)(Ad + r0 * 64), 16, 0, 0);
            const short* gb = Bt + (size_t)(n0 + r0 + srow) * ldb + (k0 + cel);
            __builtin_amdgcn_global_load_lds(
                (const __attribute__((address_space(1))) void*)gb,
                (__attribute__((address_space(3))) void*)(Bd + r0 * 64), 16, 0, 0);
        }
    };

    const int nt = K >> 6;                  // >= 4 in all uses
    stage(0, 0);
    stage(1, 64);

    for (int tt = 0; tt < nt; ++tt) {
        if (tt + 1 < nt) asm volatile("s_waitcnt vmcnt(8)" ::: "memory");
        else             asm volatile("s_waitcnt vmcnt(0)" ::: "memory");
        __builtin_amdgcn_s_barrier();
        asm volatile("" ::: "memory");

        const short* Ab = lds + (tt & 1) * 16384;
        const short* Bb = Ab + 8192;

        #pragma unroll
        for (int ks = 0; ks < 2; ++ks) {
            bf16x8 af[4], bfr[4];
            #pragma unroll
            for (int m = 0; m < 4; ++m) {
                const int rowA = wm * 64 + m * 16 + r;
                const int cb   = (ks * 64 + g * 16) ^ ((rowA & 7) << 4);
                af[m] = *(const bf16x8*)((const char*)Ab + rowA * 128 + cb);
            }
            #pragma unroll
            for (int n = 0; n < 4; ++n) {
                const int rowB = wn * 64 + n * 16 + r;
                const int cb   = (ks * 64 + g * 16) ^ ((rowB & 7) << 4);
                bfr[n] = *(const bf16x8*)((const char*)Bb + rowB * 128 + cb);
            }
            #pragma unroll
            for (int m = 0; m < 4; ++m)
                #pragma unroll
                for (int n = 0; n < 4; ++n)
                    acc[m][n] = __builtin_amdgcn_mfma_f32_16x16x32_bf16(
                        af[m], bfr[n], acc[m][n], 0, 0, 0);
        }

        asm volatile("" ::: "memory");
        __builtin_amdgcn_s_barrier();
        asm volatile("" ::: "memory");
        if (tt + 2 < nt) stage(tt & 1, (tt + 2) * 64);
    }

    // ---- epilogue: full-tile f32 via LDS (single pass), coalesced I/O ----
    __syncthreads();                        // safe drain before LDS reuse
    float* fs = (float*)lds;                // [128][128] f32 = 64 KB
    #pragma unroll
    for (int m = 0; m < 4; ++m) {
        #pragma unroll
        for (int j = 0; j < 4; ++j) {
            const int row = wm * 64 + m * 16 + g * 4 + j;
            const int rot = (row & 15) << 2;
            #pragma unroll
            for (int n = 0; n < 4; ++n) {
                const int cl = (n * 16 + r + rot) & 63;
                fs[row * 128 + wn * 64 + cl] = acc[m][n][j];
            }
        }
    }
    __syncthreads();

    const int rrow = t >> 1;                // 0..127
    const int hf   = t & 1;                 // column half
    const int gr   = m0 + rrow;
    const int rot2 = (rrow & 15) << 2;

    float vv[64];
    #pragma unroll
    for (int c4 = 0; c4 < 16; ++c4) {
        const int cl = (c4 * 4 + rot2) & 63;
        *(f32x4*)&vv[c4 * 4] = *(const f32x4*)&fs[rrow * 128 + hf * 64 + cl];
    }
    const int gc0 = n0 + hf * 64;
    if (ACCUM) {
        #pragma unroll
        for (int c8 = 0; c8 < 8; ++c8) {
            bf16x8 ci = *(const bf16x8*)(Cin + (size_t)gr * ldc + gc0 + c8 * 8);
            #pragma unroll
            for (int j = 0; j < 8; ++j) vv[c8 * 8 + j] += bf2f(ci[j]);
        }
    }
    if (BIAS) {
        #pragma unroll
        for (int c4 = 0; c4 < 16; ++c4) {
            const float4 bv = *(const float4*)(bias + gc0 + c4 * 4);
            vv[c4 * 4 + 0] += bv.x; vv[c4 * 4 + 1] += bv.y;
            vv[c4 * 4 + 2] += bv.z; vv[c4 * 4 + 3] += bv.w;
        }
    }
    if (SILU) {
        #pragma unroll
        for (int j = 0; j < 64; ++j) vv[j] = silu_f(vv[j]);
    }
    if (F32OUT) {
        if (gr < Mreal) {
            #pragma unroll
            for (int c4 = 0; c4 < 16; ++c4)
                *(float4*)((float*)Cout + (size_t)gr * ldc + gc0 + c4 * 4) =
                    make_float4(vv[c4*4+0], vv[c4*4+1], vv[c4*4+2], vv[c4*4+3]);
        }
    } else {
        #pragma unroll
        for (int c8 = 0; c8 < 8; ++c8) {
            bf16x8 o;
            #pragma unroll
            for (int j = 0; j < 8; ++j) o[j] = f2bf(vv[c8 * 8 + j]);
            *(bf16x8*)((short*)Cout + (size_t)gr * ldc + gc0 + c8 * 8) = o;
        }
    }
}

// ---------------- launcher ----------------
// Workspace (MPAD=50048): h0,h1,T,U bf16 51.25 MB each = 205.0 MB
//   + weights bf16 2.62 MB + CSR/misc ~4.5 MB  ~= 212 MB.  xb aliases T.

extern "C" void kernel_launch(void* const* d_in, const int* in_sizes, int n_in,
                              void* d_out, int out_size, void* d_ws, size_t ws_size,
                              hipStream_t stream)
{
    const float* x      = (const float*)d_in[0];
    const int*   ei     = (const int*)  d_in[1];
    const float* in_w   = (const float*)d_in[2];
    const float* in_b   = (const float*)d_in[3];
    const float* conv_w = (const float*)d_in[4];
    const float* conv_b = (const float*)d_in[5];
    const float* out_w  = (const float*)d_in[6];
    const float* out_b  = (const float*)d_in[7];

    const int N = in_sizes[0] / 256;           // 50000
    const int E = in_sizes[1] / 2;             // 400000
    const int MPAD = ((N + 127) / 128) * 128;  // 50048
    const int* row = ei;
    const int* col = ei + E;

    char* p = (char*)d_ws;
    short* h0 = (short*)p; p += (size_t)MPAD * H512 * 2;
    short* h1 = (short*)p; p += (size_t)MPAD * H512 * 2;
    short* T  = (short*)p; p += (size_t)MPAD * H512 * 2;
    short* U  = (short*)p; p += (size_t)MPAD * H512 * 2;
    short* xb = T;  // alias: xb dead before T is first written
    short* wti = (short*)p; p += (size_t)512 * 256 * 2;      // in_w^T  [512][256]
    short* wtc = (short*)p; p += (size_t)4 * 512 * 512 * 2;  // conv_w^T [4][512][512]
    short* wto = (short*)p; p += (size_t)256 * 512 * 2;      // out_w^T [256][512]
    float* deg  = (float*)p; p += (size_t)N * 4;
    float* dinv = (float*)p; p += (size_t)N * 4;
    float* ew   = (float*)p; p += (size_t)E * 4;
    int*   cnt  = (int*)p;   p += (size_t)N * 4;
    int*   ptr  = (int*)p;   p += (size_t)(N + 4) * 4;
    int*   ptr2 = (int*)p;   p += (size_t)N * 4;
    int*   esrc = (int*)p;   p += (size_t)E * 4;
    int*   bsum = (int*)p;   p += (size_t)256 * 4;
    int*   boff = (int*)p;   p += (size_t)256 * 4;

    const int NB = (N + 255) / 256;            // 196 scan blocks

    // CSR build
    hipMemsetAsync(deg, 0, (size_t)N * sizeof(float), stream);
    hipMemsetAsync(cnt, 0, (size_t)N * sizeof(int), stream);
    hist_kernel<<<(E + 255) / 256, 256, 0, stream>>>(row, col, deg, cnt, E);
    dinv_kernel<<<(N + 255) / 256, 256, 0, stream>>>(deg, dinv, N);
    bsum_kernel <<<NB, 256, 0, stream>>>(cnt, bsum, N);
    bscan_kernel<<<1, 256, 0, stream>>>(bsum, boff, NB);
    cscan_kernel<<<NB, 256, 0, stream>>>(cnt, boff, ptr, ptr2, N, NB);
    scatter_kernel<<<(E + 255) / 256, 256, 0, stream>>>(row, col, dinv, ptr2, esrc, ew, E);

    // weight/x converts (wt_kernel: grid = (K/32)*(Nw/32) 32x32 tiles)
    wt_kernel<<<(256 / 32) * (512 / 32), 256, 0, stream>>>(in_w, wti, 256, 512);
    for (int i = 0; i < 4; ++i)
        wt_kernel<<<(512 / 32) * (512 / 32), 256, 0, stream>>>(
            conv_w + (size_t)i * 512 * 512, wtc + (size_t)i * 512 * 512, 512, 512);
    wt_kernel<<<(512 / 32) * (256 / 32), 256, 0, stream>>>(out_w, wto, 512, 256);
    xconv_kernel<<<(MPAD * 32 + 255) / 256, 256, 0, stream>>>(x, xb, N, MPAD);

    const int mt = MPAD / 128;

    // h0 = silu(x @ in_w + in_b)
    mfma_gemm<0, 1, 1, 0><<<dim3(4 * mt), 256, 0, stream>>>(
        xb, 256, wti, 256, nullptr, h0, H512, in_b, N, 256, 4);

    short* hc = h0;
    short* hn = h1;
    for (int l = 0; l < 2; ++l) {
        // T = hc @ W1
        mfma_gemm<0, 0, 0, 0><<<dim3(4 * mt), 256, 0, stream>>>(
            hc, H512, wtc + (size_t)(l * 2 + 1) * 512 * 512, 512,
            nullptr, T, H512, nullptr, N, 512, 4);
        // U = Lhat @ T   (gather, no atomics)
        gather_kernel<<<(N + 3) / 4, 256, 0, stream>>>(ptr, esrc, ew, T, U, N);
        // hn = silu(hc @ W0 + U + b)
        mfma_gemm<1, 1, 1, 0><<<dim3(4 * mt), 256, 0, stream>>>(
            hc, H512, wtc + (size_t)(l * 2 + 0) * 512 * 512, 512,
            U, hn, H512, conv_b + (size_t)l * H512, N, 512, 4);
        short* tmp = hc; hc = hn; hn = tmp;
    }

    // out = hc @ out_w + out_b   (fp32, guarded)
    mfma_gemm<0, 1, 0, 1><<<dim3(2 * mt), 256, 0, stream>>>(
        hc, H512, wto, 512, nullptr, d_out, 256, out_b, N, 512, 2);
}